// Round 12
// baseline (191.842 us; speedup 1.0000x reference)
//
#include <hip/hip_runtime.h>
#include <cmath>

#define Nn    8192
#define INF_  512
#define OUTF  64

typedef __attribute__((ext_vector_type(4))) int   i4;
typedef __attribute__((ext_vector_type(4))) float f4v;
typedef __attribute__((ext_vector_type(8))) short s8;
typedef __attribute__((ext_vector_type(4))) float f32x4;
typedef unsigned long long u64;

__device__ __forceinline__ float lrelu(float v) { return fmaxf(v, 0.2f * v); }

__device__ __forceinline__ unsigned int f2bf(float f) {
    unsigned int u = __float_as_uint(f);
    u = (u + 0x7FFFu + ((u >> 16) & 1u)) >> 16;
    return u;
}

// ---------------------------------------------------------------------------
// k1: Wh = x @ W -> WhT bf16 [64][N]; Wh1 = Wh@a[:64]; Wh2 = Wh@a[64:].
// 1024 thr = 4 k-slices x 16 rows x 16 colgroups(4). Grid N/16 = 512.
// ---------------------------------------------------------------------------
__global__ __launch_bounds__(1024, 4) void k1_wh(
    const float* __restrict__ x, const float* __restrict__ W,
    const float* __restrict__ a, unsigned short* __restrict__ WhT,
    float* __restrict__ Wh1, float* __restrict__ Wh2)
{
    __shared__ float part[3][16][64];         // 12 KB k-slice partials
    __shared__ unsigned short stage[64][16];  // 2 KB bf16 transpose stage
    const int t    = threadIdx.x;
    const int s    = t >> 8;                  // k-slice 0..3
    const int r    = (t >> 4) & 15;           // row
    const int cg   = (t & 15) << 2;           // col group (4 cols)
    const int row0 = blockIdx.x * 16;
    const int row  = row0 + r;
    const float* __restrict__ xr = x + (size_t)row * INF_ + s * 128;
    const float* __restrict__ Wp = W + (size_t)s * 128 * OUTF;

    float4 acc = make_float4(0.f, 0.f, 0.f, 0.f);
    for (int k = 0; k < 128; k += 4) {
        const float4 xv = *(const float4*)(xr + k);
        const float* wp = Wp + (size_t)k * OUTF + cg;
        const float4 w0 = *(const float4*)(wp);
        const float4 w1 = *(const float4*)(wp + OUTF);
        const float4 w2 = *(const float4*)(wp + 2 * OUTF);
        const float4 w3 = *(const float4*)(wp + 3 * OUTF);
        acc.x += xv.x * w0.x + xv.y * w1.x + xv.z * w2.x + xv.w * w3.x;
        acc.y += xv.x * w0.y + xv.y * w1.y + xv.z * w2.y + xv.w * w3.y;
        acc.z += xv.x * w0.z + xv.y * w1.z + xv.z * w2.z + xv.w * w3.z;
        acc.w += xv.x * w0.w + xv.y * w1.w + xv.z * w2.w + xv.w * w3.w;
    }
    if (s > 0) *(float4*)&part[s - 1][r][cg] = acc;
    __syncthreads();
    if (s == 0) {
        const float4 pa = *(const float4*)&part[0][r][cg];
        const float4 pb = *(const float4*)&part[1][r][cg];
        const float4 pc = *(const float4*)&part[2][r][cg];
        acc.x += pa.x + pb.x + pc.x;
        acc.y += pa.y + pb.y + pc.y;
        acc.z += pa.z + pb.z + pc.z;
        acc.w += pa.w + pb.w + pc.w;
        stage[cg + 0][r] = (unsigned short)f2bf(acc.x);
        stage[cg + 1][r] = (unsigned short)f2bf(acc.y);
        stage[cg + 2][r] = (unsigned short)f2bf(acc.z);
        stage[cg + 3][r] = (unsigned short)f2bf(acc.w);

        float p1 = acc.x * a[cg]        + acc.y * a[cg + 1]
                 + acc.z * a[cg + 2]    + acc.w * a[cg + 3];
        float p2 = acc.x * a[OUTF + cg]     + acc.y * a[OUTF + cg + 1]
                 + acc.z * a[OUTF + cg + 2] + acc.w * a[OUTF + cg + 3];
        #pragma unroll
        for (int off = 8; off; off >>= 1) {
            p1 += __shfl_xor(p1, off);
            p2 += __shfl_xor(p2, off);
        }
        if ((t & 15) == 0) { Wh1[row] = p1; Wh2[row] = p2; }
    }
    __syncthreads();
    if (t < 256) {
        const int col = t >> 2;
        const int q   = t & 3;
        const u64 v = *(const u64*)&stage[col][q * 4];
        *(u64*)(WhT + (size_t)col * Nn + row0 + q * 4) = v;
    }
}

// ---------------------------------------------------------------------------
// k2: FUSED, 16 rows/block, 1024 thr = 16 waves (wave w -> row w), grid 512.
//  Pass 1 (read-bound, MFMA rides the HBM latency): per 256-j chunk:
//    adj i4 nt load (2-deep software pipeline) -> nibble -> register masks;
//    p = exp(lrelu(h1+w2)) UNNORMALIZED (PV is linear; bf16 spans e^+-50
//    fine); S += p; bf16 p -> XOR-swizzled LDS tile (dbuf); MFMA PV
//    (ct=w&3, kq=w>>2, 2 mfma/chunk, b-frags prefetched 1 chunk ahead);
//    lgkmcnt(0)+s_barrier per chunk. NO global stores in this pass.
//  Epilogue: S butterfly -> sm_is; kq-reduce via LDS; scale by is[r];
//    ELU; store out.
//  Pass 2 (write-bound, barrier-free): recompute p*is from register masks,
//    f4 nt store att. Waves free-run at full store BW.
// ---------------------------------------------------------------------------
__global__ __launch_bounds__(1024, 4) void k2_fused(
    const int* __restrict__ adj, const unsigned short* __restrict__ WhT,
    const float* __restrict__ Wh1, const float* __restrict__ Wh2,
    float* __restrict__ outp, float* __restrict__ att)
{
    __shared__ alignas(16) unsigned short att_t[2][16 * 256];  // 16 KB
    __shared__ float red[3][4][16][16];                        // 12 KB
    __shared__ float sm_is[16];

    const int t    = threadIdx.x;
    const int lane = t & 63;
    const int w    = t >> 6;               // wave = row 0..15
    const int row0 = blockIdx.x * 16;
    const int row  = row0 + w;
    const int* __restrict__ adjrow = adj + (size_t)row * Nn;
    const float h1 = Wh1[row];

    const int ct = w & 3;    // col tile (16 cols)
    const int kq = w >> 2;   // k quarter (2 of 8 ksteps per chunk)
    const int ar = lane & 15;
    const int ag = lane >> 4;

    u64 mk0 = 0, mk1 = 0;
    float S = 0.f;
    f32x4 acc = {0.f, 0.f, 0.f, 0.f};

    // produce chunk c: masks + S + bf16 p into LDS buffer bf
    auto produce = [&](int c, int bf, i4 av) {
        const f4v w2 = *((const f4v*)(Wh2 + c * 256) + lane);
        const int nib = (av.x != 0 ? 1 : 0) | (av.y != 0 ? 2 : 0)
                      | (av.z != 0 ? 4 : 0) | (av.w != 0 ? 8 : 0);
        if (c < 16) mk0 |= (u64)nib << (c * 4);
        else        mk1 |= (u64)nib << ((c - 16) * 4);
        const float p0 = (nib & 1) ? __expf(lrelu(h1 + w2.x)) : 0.f;
        const float p1 = (nib & 2) ? __expf(lrelu(h1 + w2.y)) : 0.f;
        const float p2 = (nib & 4) ? __expf(lrelu(h1 + w2.z)) : 0.f;
        const float p3 = (nib & 8) ? __expf(lrelu(h1 + w2.w)) : 0.f;
        S += (p0 + p1) + (p2 + p3);
        const u64 pk = (u64)(f2bf(p0) | (f2bf(p1) << 16))
                     | ((u64)(f2bf(p2) | (f2bf(p3) << 16)) << 32);
        int byte = w * 512 + lane * 8;  byte ^= (w & 7) << 4;
        *(u64*)((char*)att_t[bf] + byte) = pk;
    };

    auto bload = [&](int c, int ss) -> s8 {
        const int ks = kq * 2 + ss;
        return *(const s8*)(WhT + (size_t)(ct * 16 + ar) * Nn
                            + c * 256 + ks * 32 + ag * 8);
    };
    auto amfma = [&](int bf, s8 b0, s8 b1) {
        #pragma unroll
        for (int ss = 0; ss < 2; ++ss) {
            const int ks = kq * 2 + ss;
            int byte = ar * 512 + ks * 64 + ag * 16;
            byte ^= (ar & 7) << 4;
            const s8 af = *(const s8*)((char*)att_t[bf] + byte);
            acc = __builtin_amdgcn_mfma_f32_16x16x32_bf16(af, ss ? b1 : b0, acc, 0, 0, 0);
        }
    };

    // ---------------- Pass 1: scan + S + MFMA PV (no global stores) ---------
    i4 av1;
    {
        const i4 av0 = __builtin_nontemporal_load((const i4*)(adjrow) + lane);
        av1 = __builtin_nontemporal_load((const i4*)(adjrow + 256) + lane);
        produce(0, 0, av0);
    }
    s8 b0 = bload(0, 0), b1 = bload(0, 1);
    asm volatile("s_waitcnt lgkmcnt(0)" ::: "memory");
    __builtin_amdgcn_s_barrier();
    for (int c = 0; c < 31; ++c) {
        const s8 nb0 = bload(c + 1, 0);
        const s8 nb1 = bload(c + 1, 1);
        i4 av2 = {0, 0, 0, 0};
        if (c + 2 < 32)
            av2 = __builtin_nontemporal_load((const i4*)(adjrow + 256 * (c + 2)) + lane);
        produce(c + 1, (c + 1) & 1, av1);
        amfma(c & 1, b0, b1);
        asm volatile("s_waitcnt lgkmcnt(0)" ::: "memory");
        __builtin_amdgcn_s_barrier();
        av1 = av2; b0 = nb0; b1 = nb1;
    }
    amfma(31 & 1, b0, b1);

    // ---------------- Epilogue: S butterfly, kq reduce, scale, ELU ----------
    #pragma unroll
    for (int off = 32; off; off >>= 1) S += __shfl_xor(S, off);
    const float is = 1.0f / S;
    if (lane == 0) sm_is[w] = is;

    __syncthreads();
    if (kq > 0) {
        #pragma unroll
        for (int q = 0; q < 4; ++q) red[kq - 1][ct][ag * 4 + q][ar] = acc[q];
    }
    __syncthreads();
    if (kq == 0) {
        #pragma unroll
        for (int q = 0; q < 4; ++q) {
            const int r = ag * 4 + q;
            float v = acc[q] + red[0][ct][r][ar] + red[1][ct][r][ar] + red[2][ct][r][ar];
            v *= sm_is[r];
            v = v > 0.f ? v : expm1f(v);
            outp[(size_t)(row0 + r) * OUTF + ct * 16 + ar] = v;
        }
    }

    // ---------------- Pass 2: barrier-free att write stream -----------------
    float* __restrict__ arow_out = att + (size_t)row * Nn;
    for (int c = 0; c < 32; ++c) {
        const f4v w2 = *((const f4v*)(Wh2 + c * 256) + lane);
        const int nib = (int)(((c & 16) ? mk1 : mk0) >> ((c & 15) * 4)) & 15;
        f4v st;
        st.x = (nib & 1) ? __expf(lrelu(h1 + w2.x)) * is : 0.f;
        st.y = (nib & 2) ? __expf(lrelu(h1 + w2.y)) * is : 0.f;
        st.z = (nib & 4) ? __expf(lrelu(h1 + w2.z)) * is : 0.f;
        st.w = (nib & 8) ? __expf(lrelu(h1 + w2.w)) * is : 0.f;
        __builtin_nontemporal_store(st, (f4v*)(arow_out + c * 256) + lane);
    }
}

// ---------------------------------------------------------------------------
extern "C" void kernel_launch(void* const* d_in, const int* in_sizes, int n_in,
                              void* d_out, int out_size, void* d_ws, size_t ws_size,
                              hipStream_t stream)
{
    const float* x   = (const float*)d_in[0];
    const int*   adj = (const int*)d_in[1];
    const float* W   = (const float*)d_in[2];
    const float* a   = (const float*)d_in[3];

    float* outp = (float*)d_out;                       // [N, 64]
    float* att  = outp + (size_t)Nn * OUTF;            // [N, N]

    // workspace: Wh1, Wh2 (f32), WhT (bf16 [64][N])  ~1.06 MB
    float* Wh1 = (float*)d_ws;
    float* Wh2 = Wh1 + Nn;
    unsigned short* WhT = (unsigned short*)(Wh2 + Nn);

    hipLaunchKernelGGL(k1_wh,    dim3(Nn / 16), dim3(1024), 0, stream,
                       x, W, a, WhT, Wh1, Wh2);
    hipLaunchKernelGGL(k2_fused, dim3(Nn / 16), dim3(1024), 0, stream,
                       adj, WhT, Wh1, Wh2, outp, att);
}

// Round 13
// 179.027 us; speedup vs baseline: 1.0716x; 1.0716x over previous
//
#include <hip/hip_runtime.h>
#include <cmath>

#define Nn    8192
#define INF_  512
#define OUTF  64

typedef __attribute__((ext_vector_type(4))) int   i4;
typedef __attribute__((ext_vector_type(4))) float f4v;
typedef __attribute__((ext_vector_type(8))) short s8;
typedef __attribute__((ext_vector_type(4))) float f32x4;
typedef unsigned long long u64;

__device__ __forceinline__ float lrelu(float v) { return fmaxf(v, 0.2f * v); }

__device__ __forceinline__ unsigned int f2bf(float f) {
    unsigned int u = __float_as_uint(f);
    u = (u + 0x7FFFu + ((u >> 16) & 1u)) >> 16;
    return u;
}

// ---------------------------------------------------------------------------
// k1: Wh = x @ W -> WhT bf16 [64][N]; Wh1 = Wh@a[:64]; Wh2 = Wh@a[64:].
// 1024 thr = 4 k-slices x 16 rows x 16 colgroups(4). Grid N/16 = 512.
// (identical to R9's k1; (1024,8) bounds — R12's (1024,4) regressed it)
// ---------------------------------------------------------------------------
__global__ __launch_bounds__(1024, 8) void k1_wh(
    const float* __restrict__ x, const float* __restrict__ W,
    const float* __restrict__ a, unsigned short* __restrict__ WhT,
    float* __restrict__ Wh1, float* __restrict__ Wh2)
{
    __shared__ float part[3][16][64];         // 12 KB k-slice partials
    __shared__ unsigned short stage[64][16];  // 2 KB bf16 transpose stage
    const int t    = threadIdx.x;
    const int s    = t >> 8;                  // k-slice 0..3
    const int r    = (t >> 4) & 15;           // row
    const int cg   = (t & 15) << 2;           // col group (4 cols)
    const int row0 = blockIdx.x * 16;
    const int row  = row0 + r;
    const float* __restrict__ xr = x + (size_t)row * INF_ + s * 128;
    const float* __restrict__ Wp = W + (size_t)s * 128 * OUTF;

    float4 acc = make_float4(0.f, 0.f, 0.f, 0.f);
    for (int k = 0; k < 128; k += 4) {
        const float4 xv = *(const float4*)(xr + k);
        const float* wp = Wp + (size_t)k * OUTF + cg;
        const float4 w0 = *(const float4*)(wp);
        const float4 w1 = *(const float4*)(wp + OUTF);
        const float4 w2 = *(const float4*)(wp + 2 * OUTF);
        const float4 w3 = *(const float4*)(wp + 3 * OUTF);
        acc.x += xv.x * w0.x + xv.y * w1.x + xv.z * w2.x + xv.w * w3.x;
        acc.y += xv.x * w0.y + xv.y * w1.y + xv.z * w2.y + xv.w * w3.y;
        acc.z += xv.x * w0.z + xv.y * w1.z + xv.z * w2.z + xv.w * w3.z;
        acc.w += xv.x * w0.w + xv.y * w1.w + xv.z * w2.w + xv.w * w3.w;
    }
    if (s > 0) *(float4*)&part[s - 1][r][cg] = acc;
    __syncthreads();
    if (s == 0) {
        const float4 pa = *(const float4*)&part[0][r][cg];
        const float4 pb = *(const float4*)&part[1][r][cg];
        const float4 pc = *(const float4*)&part[2][r][cg];
        acc.x += pa.x + pb.x + pc.x;
        acc.y += pa.y + pb.y + pc.y;
        acc.z += pa.z + pb.z + pc.z;
        acc.w += pa.w + pb.w + pc.w;
        stage[cg + 0][r] = (unsigned short)f2bf(acc.x);
        stage[cg + 1][r] = (unsigned short)f2bf(acc.y);
        stage[cg + 2][r] = (unsigned short)f2bf(acc.z);
        stage[cg + 3][r] = (unsigned short)f2bf(acc.w);

        float p1 = acc.x * a[cg]        + acc.y * a[cg + 1]
                 + acc.z * a[cg + 2]    + acc.w * a[cg + 3];
        float p2 = acc.x * a[OUTF + cg]     + acc.y * a[OUTF + cg + 1]
                 + acc.z * a[OUTF + cg + 2] + acc.w * a[OUTF + cg + 3];
        #pragma unroll
        for (int off = 8; off; off >>= 1) {
            p1 += __shfl_xor(p1, off);
            p2 += __shfl_xor(p2, off);
        }
        if ((t & 15) == 0) { Wh1[row] = p1; Wh2[row] = p2; }
    }
    __syncthreads();
    if (t < 256) {
        const int col = t >> 2;
        const int q   = t & 3;
        const u64 v = *(const u64*)&stage[col][q * 4];
        *(u64*)(WhT + (size_t)col * Nn + row0 + q * 4) = v;
    }
}

// ---------------------------------------------------------------------------
// k2: FUSED, 16 rows/block, 1024 thr = 16 waves (wave w -> row w), grid 512.
//  Phase A (CHANGED vs R9 — the single lever): adj scan with REGULAR cached
//    loads (no nontemporal: nt evict-first policy defeated L2/L3 reuse; every
//    scan since R2 was nt and stuck at ~2.2 TB/s) + explicit 4-deep rotating
//    prefetch (guaranteed 4 outstanding 1KB loads/wave). Masks mk0/mk1 +
//    fused S (no max subtraction; logits bounded ~60).
//  Phase B (identical to R9): per 256-j chunk: att = bit?exp/S:0; f32 nt
//    store in-loop + bf16 XOR-swizzled LDS tile dbuf; MFMA PV (ct=w&3,
//    kq=w>>2, 2 mfma/chunk, b-frags prefetched 1 chunk ahead);
//    lgkmcnt(0)+s_barrier per chunk.
//  Epilogue: 4-way kq reduce via LDS, ELU, store out.
// ---------------------------------------------------------------------------
__global__ __launch_bounds__(1024, 8) void k2_fused(
    const int* __restrict__ adj, const unsigned short* __restrict__ WhT,
    const float* __restrict__ Wh1, const float* __restrict__ Wh2,
    float* __restrict__ outp, float* __restrict__ att)
{
    __shared__ alignas(16) unsigned short att_t[2][16 * 256];  // 16 KB
    __shared__ float red[3][4][16][16];                        // 12 KB

    const int t    = threadIdx.x;
    const int lane = t & 63;
    const int w    = t >> 6;               // wave = row 0..15
    const int row0 = blockIdx.x * 16;
    const int row  = row0 + w;
    const int* __restrict__ adjrow = adj + (size_t)row * Nn;
    const float h1 = Wh1[row];

    // ---------------- Phase A: cached 4-deep pipelined adj scan -------------
    u64 mk0 = 0, mk1 = 0;
    float S = 0.f;
    {
        i4 av[4];
        #pragma unroll
        for (int i = 0; i < 4; ++i)
            av[i] = *((const i4*)(adjrow + 256 * i) + lane);
        #pragma unroll
        for (int i = 0; i < 32; ++i) {
            const i4 a = av[i & 3];
            if (i < 28)
                av[i & 3] = *((const i4*)(adjrow + 256 * (i + 4)) + lane);
            const f4v w4 = *((const f4v*)(Wh2 + 256 * i) + lane);
            const int nib = (a.x != 0 ? 1 : 0) | (a.y != 0 ? 2 : 0)
                          | (a.z != 0 ? 4 : 0) | (a.w != 0 ? 8 : 0);
            S += (nib & 1) ? __expf(lrelu(h1 + w4.x)) : 0.f;
            S += (nib & 2) ? __expf(lrelu(h1 + w4.y)) : 0.f;
            S += (nib & 4) ? __expf(lrelu(h1 + w4.z)) : 0.f;
            S += (nib & 8) ? __expf(lrelu(h1 + w4.w)) : 0.f;
            if (i < 16) mk0 |= (u64)nib << (i * 4);
            else        mk1 |= (u64)nib << ((i - 16) * 4);
        }
    }
    #pragma unroll
    for (int off = 32; off; off >>= 1) S += __shfl_xor(S, off);
    const float is = 1.0f / S;

    // ---------------- Phase B: att stores + bf16 LDS + MFMA PV --------------
    const int ct = w & 3;    // col tile (16 cols)
    const int kq = w >> 2;   // k quarter (2 of 8 ksteps per chunk)
    f32x4 acc = {0.f, 0.f, 0.f, 0.f};

    auto produce = [&](int c, int bf) {
        const int jb = c * 256;
        const f4v w2 = *((const f4v*)(Wh2 + jb) + lane);
        const int nib = (int)(((c & 16) ? mk1 : mk0) >> ((c & 15) * 4)) & 15;
        const float v0 = (nib & 1) ? __expf(lrelu(h1 + w2.x)) * is : 0.f;
        const float v1 = (nib & 2) ? __expf(lrelu(h1 + w2.y)) * is : 0.f;
        const float v2 = (nib & 4) ? __expf(lrelu(h1 + w2.z)) * is : 0.f;
        const float v3 = (nib & 8) ? __expf(lrelu(h1 + w2.w)) * is : 0.f;
        f4v st; st.x = v0; st.y = v1; st.z = v2; st.w = v3;
        __builtin_nontemporal_store(st, (f4v*)(att + (size_t)row * Nn + jb) + lane);
        const u64 pk = (u64)(f2bf(v0) | (f2bf(v1) << 16))
                     | ((u64)(f2bf(v2) | (f2bf(v3) << 16)) << 32);
        int byte = w * 512 + lane * 8;  byte ^= (w & 7) << 4;
        *(u64*)((char*)att_t[bf] + byte) = pk;
    };

    const int ar = lane & 15;    // MFMA A-row / B-row this lane reads
    const int ag = lane >> 4;    // k-subgroup
    auto bload = [&](int c, int ss) -> s8 {
        const int ks = kq * 2 + ss;
        return *(const s8*)(WhT + (size_t)(ct * 16 + ar) * Nn
                            + c * 256 + ks * 32 + ag * 8);
    };
    auto amfma = [&](int bf, s8 b0, s8 b1) {
        #pragma unroll
        for (int ss = 0; ss < 2; ++ss) {
            const int ks = kq * 2 + ss;
            int byte = ar * 512 + ks * 64 + ag * 16;
            byte ^= (ar & 7) << 4;
            const s8 af = *(const s8*)((char*)att_t[bf] + byte);
            acc = __builtin_amdgcn_mfma_f32_16x16x32_bf16(af, ss ? b1 : b0, acc, 0, 0, 0);
        }
    };

    s8 b0 = bload(0, 0), b1 = bload(0, 1);
    produce(0, 0);
    asm volatile("s_waitcnt lgkmcnt(0)" ::: "memory");
    __builtin_amdgcn_s_barrier();
    for (int c = 0; c < Nn / 256 - 1; ++c) {
        produce(c + 1, (c + 1) & 1);
        const s8 nb0 = bload(c + 1, 0);
        const s8 nb1 = bload(c + 1, 1);
        amfma(c & 1, b0, b1);
        asm volatile("s_waitcnt lgkmcnt(0)" ::: "memory");
        __builtin_amdgcn_s_barrier();
        b0 = nb0; b1 = nb1;
    }
    amfma((Nn / 256 - 1) & 1, b0, b1);

    // ---------------- Epilogue: kq reduce + scale + ELU + out store ---------
    __syncthreads();
    if (kq > 0) {
        #pragma unroll
        for (int q = 0; q < 4; ++q) red[kq - 1][ct][ag * 4 + q][ar] = acc[q];
    }
    __syncthreads();
    if (kq == 0) {
        #pragma unroll
        for (int q = 0; q < 4; ++q) {
            const int r = ag * 4 + q;
            float v = acc[q] + red[0][ct][r][ar] + red[1][ct][r][ar] + red[2][ct][r][ar];
            v = v > 0.f ? v : expm1f(v);
            outp[(size_t)(row0 + r) * OUTF + ct * 16 + ar] = v;
        }
    }
}

// ---------------------------------------------------------------------------
extern "C" void kernel_launch(void* const* d_in, const int* in_sizes, int n_in,
                              void* d_out, int out_size, void* d_ws, size_t ws_size,
                              hipStream_t stream)
{
    const float* x   = (const float*)d_in[0];
    const int*   adj = (const int*)d_in[1];
    const float* W   = (const float*)d_in[2];
    const float* a   = (const float*)d_in[3];

    float* outp = (float*)d_out;                       // [N, 64]
    float* att  = outp + (size_t)Nn * OUTF;            // [N, N]

    // workspace: Wh1, Wh2 (f32), WhT (bf16 [64][N])  ~1.06 MB
    float* Wh1 = (float*)d_ws;
    float* Wh2 = Wh1 + Nn;
    unsigned short* WhT = (unsigned short*)(Wh2 + Nn);

    hipLaunchKernelGGL(k1_wh,    dim3(Nn / 16), dim3(1024), 0, stream,
                       x, W, a, WhT, Wh1, Wh2);
    hipLaunchKernelGGL(k2_fused, dim3(Nn / 16), dim3(1024), 0, stream,
                       adj, WhT, Wh1, Wh2, outp, att);
}

// Round 15
// 161.966 us; speedup vs baseline: 1.1845x; 1.1053x over previous
//
#include <hip/hip_runtime.h>
#include <cmath>

#define Nn    8192
#define INF_  512
#define OUTF  64

typedef __attribute__((ext_vector_type(4))) int   i4;
typedef __attribute__((ext_vector_type(4))) float f4v;
typedef __attribute__((ext_vector_type(8))) short s8;
typedef __attribute__((ext_vector_type(4))) float f32x4;
typedef unsigned long long u64;

__device__ __forceinline__ float lrelu(float v) { return fmaxf(v, 0.2f * v); }

__device__ __forceinline__ unsigned int f2bf(float f) {
    unsigned int u = __float_as_uint(f);
    u = (u + 0x7FFFu + ((u >> 16) & 1u)) >> 16;
    return u;
}

// ---------------------------------------------------------------------------
// k1: Wh = x @ W -> WhT bf16 [64][N]; Wh1 = Wh@a[:64]; Wh2 = Wh@a[64:].
// DENSE x read: block loads its 16-row slab (32 KB contiguous) to LDS in two
// 16 KB steps, then GEMM from LDS (pad 520 kills the 4-row bank aliasing).
// 1024 thr = 4 k-slices x 16 rows x 16 colgroups(4). Grid N/16 = 512.
// ---------------------------------------------------------------------------
__global__ __launch_bounds__(1024, 8) void k1_wh(
    const float* __restrict__ x, const float* __restrict__ W,
    const float* __restrict__ a, unsigned short* __restrict__ WhT,
    float* __restrict__ Wh1, float* __restrict__ Wh2)
{
    __shared__ float xs[16][520];             // 33.3 KB x slab (padded)
    __shared__ float part[3][16][64];         // 12 KB k-slice partials
    __shared__ unsigned short stage[64][16];  // 2 KB bf16 transpose stage
    const int t    = threadIdx.x;
    const int row0 = blockIdx.x * 16;

    // dense cooperative slab load: 2 steps x 16 KB contiguous
    #pragma unroll
    for (int s2 = 0; s2 < 2; ++s2) {
        const int idx = s2 * 4096 + 4 * t;
        const f4v v = __builtin_nontemporal_load(
            (const f4v*)(x + (size_t)row0 * INF_ + idx));
        *(f4v*)&xs[idx >> 9][idx & 511] = v;
    }
    __syncthreads();

    const int s    = t >> 8;                  // k-slice 0..3
    const int r    = (t >> 4) & 15;           // row
    const int cg   = (t & 15) << 2;           // col group (4 cols)
    const int row  = row0 + r;
    const float* __restrict__ Wp = W + (size_t)s * 128 * OUTF;

    float4 acc = make_float4(0.f, 0.f, 0.f, 0.f);
    for (int k = 0; k < 128; k += 4) {
        const float4 xv = *(const float4*)&xs[r][s * 128 + k];
        const float* wp = Wp + (size_t)k * OUTF + cg;
        const float4 w0 = *(const float4*)(wp);
        const float4 w1 = *(const float4*)(wp + OUTF);
        const float4 w2 = *(const float4*)(wp + 2 * OUTF);
        const float4 w3 = *(const float4*)(wp + 3 * OUTF);
        acc.x += xv.x * w0.x + xv.y * w1.x + xv.z * w2.x + xv.w * w3.x;
        acc.y += xv.x * w0.y + xv.y * w1.y + xv.z * w2.y + xv.w * w3.y;
        acc.z += xv.x * w0.z + xv.y * w1.z + xv.z * w2.z + xv.w * w3.z;
        acc.w += xv.x * w0.w + xv.y * w1.w + xv.z * w2.w + xv.w * w3.w;
    }
    if (s > 0) *(float4*)&part[s - 1][r][cg] = acc;
    __syncthreads();
    if (s == 0) {
        const float4 pa = *(const float4*)&part[0][r][cg];
        const float4 pb = *(const float4*)&part[1][r][cg];
        const float4 pc = *(const float4*)&part[2][r][cg];
        acc.x += pa.x + pb.x + pc.x;
        acc.y += pa.y + pb.y + pc.y;
        acc.z += pa.z + pb.z + pc.z;
        acc.w += pa.w + pb.w + pc.w;
        stage[cg + 0][r] = (unsigned short)f2bf(acc.x);
        stage[cg + 1][r] = (unsigned short)f2bf(acc.y);
        stage[cg + 2][r] = (unsigned short)f2bf(acc.z);
        stage[cg + 3][r] = (unsigned short)f2bf(acc.w);

        float p1 = acc.x * a[cg]        + acc.y * a[cg + 1]
                 + acc.z * a[cg + 2]    + acc.w * a[cg + 3];
        float p2 = acc.x * a[OUTF + cg]     + acc.y * a[OUTF + cg + 1]
                 + acc.z * a[OUTF + cg + 2] + acc.w * a[OUTF + cg + 3];
        #pragma unroll
        for (int off = 8; off; off >>= 1) {
            p1 += __shfl_xor(p1, off);
            p2 += __shfl_xor(p2, off);
        }
        if ((t & 15) == 0) { Wh1[row] = p1; Wh2[row] = p2; }
    }
    __syncthreads();
    if (t < 256) {
        const int col = t >> 2;
        const int q   = t & 3;
        const u64 v = *(const u64*)&stage[col][q * 4];
        *(u64*)(WhT + (size_t)col * Nn + row0 + q * 4) = v;
    }
}

// ---------------------------------------------------------------------------
// k2: FUSED, 16 rows/block, 1024 thr = 16 waves, grid N/16 = 512.
//  Sweep (DENSE, the lever): block reads its 512 KB adj slab LINEARLY,
//    16 KB/step (32 steps, 2 steps per row, no barriers): thread t takes
//    ints [s*4096+4t..+4) -> nibble byte into LDS bm8[16][2048]; masked
//    exp-sum partial per thread, butterfly-flushed at each row boundary
//    -> sm_Sp[row][wave]. 512 dense streams device-wide instead of 8192
//    32KB-strided ones (the 2.2 TB/s invariant suspect).
//  S-finish: wave w reduces sm_Sp[w][0..15] -> sm_is[w] = 1/S.
//  Phase B (R9 exact, masks from bm8): per 256-j chunk: att = bit ?
//    exp(lrelu(h1+w2))*is : 0; f32 nt store in-loop + bf16 XOR-swizzled
//    LDS tile dbuf; MFMA PV (ct=w&3, kq=w>>2, 2 mfma/chunk, 1-chunk b-frag
//    prefetch); lgkmcnt(0)+s_barrier per chunk.
//  Epilogue: 4-way kq reduce via LDS, ELU, store out.
// ---------------------------------------------------------------------------
__global__ __launch_bounds__(1024, 8) void k2_fused(
    const int* __restrict__ adj, const unsigned short* __restrict__ WhT,
    const float* __restrict__ Wh1, const float* __restrict__ Wh2,
    float* __restrict__ outp, float* __restrict__ att)
{
    __shared__ unsigned char bm8[16][2048];                    // 32 KB masks
    __shared__ alignas(16) unsigned short att_t[2][16 * 256];  // 16 KB
    __shared__ float red[3][4][16][16];                        // 12 KB
    __shared__ float sm_Sp[16][16];                            // 1 KB
    __shared__ float sm_is[16];

    const int t    = threadIdx.x;
    const int lane = t & 63;
    const int w    = t >> 6;               // wave id; phase B row = w
    const int row0 = blockIdx.x * 16;

    // ---------------- Dense cooperative adj sweep ---------------------------
    {
        const i4* __restrict__ asrc = (const i4*)(adj + (size_t)row0 * Nn);
        const int j0 = 4 * t;                       // j within half-row
        const f4v w4a = *(const f4v*)(Wh2 + j0);            // half 0 cols
        const f4v w4b = *(const f4v*)(Wh2 + 4096 + j0);     // half 1 cols
        float Sp = 0.f;
        i4 av = __builtin_nontemporal_load(asrc + t);       // step 0
        #pragma unroll
        for (int s = 0; s < 32; ++s) {
            const int r = s >> 1, h = s & 1;
            i4 nxt;
            if (s < 31)
                nxt = __builtin_nontemporal_load(asrc + (s + 1) * 1024 + t);
            const f4v w4 = h ? w4b : w4a;
            const float h1r = Wh1[row0 + r];
            const int nib = (av.x != 0 ? 1 : 0) | (av.y != 0 ? 2 : 0)
                          | (av.z != 0 ? 4 : 0) | (av.w != 0 ? 8 : 0);
            Sp += (nib & 1) ? __expf(lrelu(h1r + w4.x)) : 0.f;
            Sp += (nib & 2) ? __expf(lrelu(h1r + w4.y)) : 0.f;
            Sp += (nib & 4) ? __expf(lrelu(h1r + w4.z)) : 0.f;
            Sp += (nib & 8) ? __expf(lrelu(h1r + w4.w)) : 0.f;
            bm8[r][h * 1024 + t] = (unsigned char)nib;
            if (h) {   // row r complete for this thread: flush partial
                #pragma unroll
                for (int off = 32; off; off >>= 1) Sp += __shfl_xor(Sp, off);
                if (lane == 0) sm_Sp[r][w] = Sp;
                Sp = 0.f;
            }
            av = nxt;
        }
    }
    __syncthreads();

    // ---------------- S finish: wave w reduces row w ------------------------
    {
        float sv = sm_Sp[w][lane & 15];
        #pragma unroll
        for (int off = 8; off; off >>= 1) sv += __shfl_xor(sv, off);
        if (lane == 0) sm_is[w] = 1.0f / sv;
    }
    __syncthreads();

    const int row = row0 + w;
    const float h1 = Wh1[row];
    const float is = sm_is[w];

    // ---------------- Phase B: att stores + bf16 LDS + MFMA PV --------------
    const int ct = w & 3;    // col tile (16 cols)
    const int kq = w >> 2;   // k quarter (2 of 8 ksteps per chunk)
    f32x4 acc = {0.f, 0.f, 0.f, 0.f};

    auto produce = [&](int c, int bf) {
        const int jb = c * 256;
        const f4v w2 = *((const f4v*)(Wh2 + jb) + lane);
        const int nib = bm8[w][c * 64 + lane];
        const float v0 = (nib & 1) ? __expf(lrelu(h1 + w2.x)) * is : 0.f;
        const float v1 = (nib & 2) ? __expf(lrelu(h1 + w2.y)) * is : 0.f;
        const float v2 = (nib & 4) ? __expf(lrelu(h1 + w2.z)) * is : 0.f;
        const float v3 = (nib & 8) ? __expf(lrelu(h1 + w2.w)) * is : 0.f;
        f4v st; st.x = v0; st.y = v1; st.z = v2; st.w = v3;
        __builtin_nontemporal_store(st, (f4v*)(att + (size_t)row * Nn + jb) + lane);
        const u64 pk = (u64)(f2bf(v0) | (f2bf(v1) << 16))
                     | ((u64)(f2bf(v2) | (f2bf(v3) << 16)) << 32);
        int byte = w * 512 + lane * 8;  byte ^= (w & 7) << 4;
        *(u64*)((char*)att_t[bf] + byte) = pk;
    };

    const int ar = lane & 15;    // MFMA A-row / B-row this lane reads
    const int ag = lane >> 4;    // k-subgroup
    auto bload = [&](int c, int ss) -> s8 {
        const int ks = kq * 2 + ss;
        return *(const s8*)(WhT + (size_t)(ct * 16 + ar) * Nn
                            + c * 256 + ks * 32 + ag * 8);
    };
    auto amfma = [&](int bf, s8 b0, s8 b1) {
        #pragma unroll
        for (int ss = 0; ss < 2; ++ss) {
            const int ks = kq * 2 + ss;
            int byte = ar * 512 + ks * 64 + ag * 16;
            byte ^= (ar & 7) << 4;
            const s8 af = *(const s8*)((char*)att_t[bf] + byte);
            acc = __builtin_amdgcn_mfma_f32_16x16x32_bf16(af, ss ? b1 : b0, acc, 0, 0, 0);
        }
    };

    s8 b0 = bload(0, 0), b1 = bload(0, 1);
    produce(0, 0);
    asm volatile("s_waitcnt lgkmcnt(0)" ::: "memory");
    __builtin_amdgcn_s_barrier();
    for (int c = 0; c < Nn / 256 - 1; ++c) {
        produce(c + 1, (c + 1) & 1);
        const s8 nb0 = bload(c + 1, 0);
        const s8 nb1 = bload(c + 1, 1);
        amfma(c & 1, b0, b1);
        asm volatile("s_waitcnt lgkmcnt(0)" ::: "memory");
        __builtin_amdgcn_s_barrier();
        b0 = nb0; b1 = nb1;
    }
    amfma((Nn / 256 - 1) & 1, b0, b1);

    // ---------------- Epilogue: kq reduce + ELU + out store -----------------
    __syncthreads();
    if (kq > 0) {
        #pragma unroll
        for (int q = 0; q < 4; ++q) red[kq - 1][ct][ag * 4 + q][ar] = acc[q];
    }
    __syncthreads();
    if (kq == 0) {
        #pragma unroll
        for (int q = 0; q < 4; ++q) {
            const int r = ag * 4 + q;
            float v = acc[q] + red[0][ct][r][ar] + red[1][ct][r][ar] + red[2][ct][r][ar];
            v = v > 0.f ? v : expm1f(v);
            outp[(size_t)(row0 + r) * OUTF + ct * 16 + ar] = v;
        }
    }
}

// ---------------------------------------------------------------------------
extern "C" void kernel_launch(void* const* d_in, const int* in_sizes, int n_in,
                              void* d_out, int out_size, void* d_ws, size_t ws_size,
                              hipStream_t stream)
{
    const float* x   = (const float*)d_in[0];
    const int*   adj = (const int*)d_in[1];
    const float* W   = (const float*)d_in[2];
    const float* a   = (const float*)d_in[3];

    float* outp = (float*)d_out;                       // [N, 64]
    float* att  = outp + (size_t)Nn * OUTF;            // [N, N]

    // workspace: Wh1, Wh2 (f32), WhT (bf16 [64][N])  ~1.06 MB
    float* Wh1 = (float*)d_ws;
    float* Wh2 = Wh1 + Nn;
    unsigned short* WhT = (unsigned short*)(Wh2 + Nn);

    hipLaunchKernelGGL(k1_wh,    dim3(Nn / 16), dim3(1024), 0, stream,
                       x, W, a, WhT, Wh1, Wh2);
    hipLaunchKernelGGL(k2_fused, dim3(Nn / 16), dim3(1024), 0, stream,
                       adj, WhT, Wh1, Wh2, outp, att);
}